// Round 1
// baseline (67.125 us; speedup 1.0000x reference)
//
#include <hip/hip_runtime.h>

typedef float f32x4 __attribute__((ext_vector_type(4)));
typedef short bf16x8 __attribute__((ext_vector_type(8)));

#define NB   16
#define CIN  32
#define HW   64
#define CKK  288
#define QD   64

// ws layout (ushort elems): Ws[64][288] @0, Mc[128][64] @36864, Wout[64][64] @45056
#define WS_OFF_MC 36864
#define WS_OFF_WO (36864 + 8192)

__device__ __forceinline__ unsigned short f2bf(float f) {
  unsigned u = __builtin_bit_cast(unsigned, f);
  u += 0x7FFFu + ((u >> 16) & 1u);   // RNE
  return (unsigned short)(u >> 16);
}

struct C2 { float r, i; };
struct M2 { C2 a, b, c, d; };  // [[a,b],[c,d]]

__device__ __forceinline__ C2 cmul(C2 x, C2 y) { return { x.r*y.r - x.i*y.i, x.r*y.i + x.i*y.r }; }
__device__ __forceinline__ C2 cadd(C2 x, C2 y) { return { x.r + y.r, x.i + y.i }; }
__device__ __forceinline__ M2 mmul(M2 X, M2 Y) {  // X*Y (Y applied first)
  return { cadd(cmul(X.a, Y.a), cmul(X.b, Y.c)),
           cadd(cmul(X.a, Y.b), cmul(X.b, Y.d)),
           cadd(cmul(X.c, Y.a), cmul(X.d, Y.c)),
           cadd(cmul(X.c, Y.b), cmul(X.d, Y.d)) };
}

__device__ __forceinline__ M2 mRX(float t) {
  float s, c; __sincosf(t * 0.5f, &s, &c);
  return { {c,0.f}, {0.f,-s}, {0.f,-s}, {c,0.f} };
}
__device__ __forceinline__ M2 mRY(float t) {
  float s, c; __sincosf(t * 0.5f, &s, &c);
  return { {c,0.f}, {-s,0.f}, {s,0.f}, {c,0.f} };
}
__device__ __forceinline__ M2 mU3(float t, float p, float lm) {
  float s, c; __sincosf(t * 0.5f, &s, &c);
  float sp, cp; __sincosf(p, &sp, &cp);
  float sl, cl; __sincosf(lm, &sl, &cl);
  float spl, cpl; __sincosf(p + lm, &spl, &cpl);
  return { {c,0.f}, {-cl*s, -sl*s}, {cp*s, sp*s}, {cpl*c, spl*c} };
}

// one block, 256 threads: build bf16 Ws/Wout, and the 64x64 circuit matrix
__global__ __launch_bounds__(256) void prep_kernel(
    const float* __restrict__ in_proj_w, const float* __restrict__ inp_scale,
    const float* __restrict__ weights, const float* __restrict__ meas_w,
    const float* __restrict__ out_proj_w, unsigned short* __restrict__ ws)
{
  const int tid = threadIdx.x, lane = tid & 63, wid = tid >> 6;

  for (int e = tid; e < QD * CKK; e += 256)
    ws[e] = f2bf(in_proj_w[e] * inp_scale[e % CKK]);
  unsigned short* Wo = ws + WS_OFF_WO;
  for (int e = tid; e < QD * QD; e += 256)
    Wo[e] = f2bf(out_proj_w[e]);

  // circuit: lane = state row (0..63); this wave owns columns [wid*16, wid*16+16)
  float mre[16], mim[16];
#pragma unroll
  for (int j = 0; j < 16; ++j) { mre[j] = (lane == wid * 16 + j) ? 1.f : 0.f; mim[j] = 0.f; }

  auto apply = [&](int bit, M2 U) {
    int rb = (lane >> bit) & 1;
    float arr = rb ? U.d.r : U.a.r, ari = rb ? U.d.i : U.a.i;   // coeff on own value
    float brr = rb ? U.c.r : U.b.r, bri = rb ? U.c.i : U.b.i;   // coeff on partner
#pragma unroll
    for (int j = 0; j < 16; ++j) {
      float pre = __shfl_xor(mre[j], 1 << bit);
      float pim = __shfl_xor(mim[j], 1 << bit);
      float nr = arr * mre[j] - ari * mim[j] + brr * pre - bri * pim;
      float ni = arr * mim[j] + ari * mre[j] + brr * pim + bri * pre;
      mre[j] = nr; mim[j] = ni;
    }
  };
  auto cnot = [&](int wire) {
    int cb = 5 - wire, tb = 4 - wire;
    int ctrl = (lane >> cb) & 1;
#pragma unroll
    for (int j = 0; j < 16; ++j) {
      float pre = __shfl_xor(mre[j], 1 << tb);
      float pim = __shfl_xor(mim[j], 1 << tb);
      mre[j] = ctrl ? pre : mre[j];
      mim[j] = ctrl ? pim : mim[j];
    }
  };

  for (int l = 0; l < 2; ++l) {
    for (int q = 0; q < 6; ++q) {
      const float* wp = weights + (l * 6 + q) * 3;
      apply(5 - q, mmul(mRY(wp[1]), mRX(wp[0])));   // RX then RY
    }
    for (int q = 0; q < 5; ++q) cnot(q);
    for (int q = 0; q < 6; ++q) {
      const float* wp = weights + (l * 6 + q) * 3;
      M2 g = mRY(wp[2]);
      if (l == 1) {  // fold the (commuting) measurement U3 into layer-2 trailing RY
        const float* mp = meas_w + q * 3;
        g = mmul(mU3(mp[0], mp[1], mp[2]), g);
      }
      apply(5 - q, g);
    }
  }

  unsigned short* Mc = ws + WS_OFF_MC;   // rows 0..63: Re M, rows 64..127: Im M ; [j][n]
#pragma unroll
  for (int j = 0; j < 16; ++j) {
    int col = wid * 16 + j;
    Mc[lane * 64 + col]        = f2bf(mre[j]);
    Mc[(64 + lane) * 64 + col] = f2bf(mim[j]);
  }
}

#define LDA 72   // bf16 elems per row (pad 64->72, 16B-aligned rows, conflict-benign)
#define LDO 65   // f32 elems per row for output transpose

__global__ __launch_bounds__(256) void main_kernel(
    const float* __restrict__ x, const float* __restrict__ b_in,
    const float* __restrict__ b_out, const unsigned short* __restrict__ ws,
    float* __restrict__ out)
{
  __shared__ __align__(16) unsigned char smem[18432];
  unsigned short* a_lds = (unsigned short*)smem;             // [64][72] amplitudes
  unsigned short* p_lds = (unsigned short*)(smem + 9216);    // [64][72] probs
  float* o_lds = (float*)smem;                               // [64][65] output (reuses both)

  const int tid = threadIdx.x, lane = tid & 63, wid = tid >> 6;
  const int g = lane >> 4, c16 = lane & 15;
  const int blk = blockIdx.x;
  const int b = blk >> 6, h = blk & 63;

  const unsigned short* Ws = ws;
  const unsigned short* Mc = ws + WS_OFF_MC;
  const unsigned short* Wo = ws + WS_OFF_WO;

  // ---- GEMM1: xq[64 pix][64] = patch(64x288) * Ws^T + b_in ----
  f32x4 acc[4];
#pragma unroll
  for (int jt = 0; jt < 4; ++jt) { float bi = b_in[jt * 16 + c16]; acc[jt] = f32x4{bi, bi, bi, bi}; }

  const int ar = wid * 16 + c16;              // this lane's A-row = pixel w
  const float* xb = x + b * CIN * HW * HW;
#pragma unroll
  for (int kk = 0; kk < 9; ++kk) {
    bf16x8 af;
#pragma unroll
    for (int i = 0; i < 8; ++i) {
      int k = kk * 32 + g * 8 + i;           // patch index: c*9 + di*3 + dj
      int cc = k / 9, rr = k - cc * 9;
      int di = rr / 3, dj = rr - di * 3;
      int y = h + di - 1, xw = ar + dj - 1;
      float v = 0.f;
      if ((unsigned)y < 64u && (unsigned)xw < 64u) v = xb[(cc * 64 + y) * 64 + xw];
      af[i] = (short)f2bf(v);
    }
#pragma unroll
    for (int jt = 0; jt < 4; ++jt) {
      bf16x8 bf_ = *(const bf16x8*)(Ws + (jt * 16 + c16) * CKK + kk * 32 + g * 8);
      acc[jt] = __builtin_amdgcn_mfma_f32_16x16x32_bf16(af, bf_, acc[jt], 0, 0, 0);
    }
  }

  // ---- row norm (C layout: col=lane&15, row=(lane>>4)*4+reg) ----
  float s[4];
#pragma unroll
  for (int r = 0; r < 4; ++r) {
    float t = acc[0][r] * acc[0][r] + acc[1][r] * acc[1][r] +
              acc[2][r] * acc[2][r] + acc[3][r] * acc[3][r];
    t += __shfl_xor(t, 1); t += __shfl_xor(t, 2); t += __shfl_xor(t, 4); t += __shfl_xor(t, 8);
    s[r] = 1.f / (sqrtf(t) + 1e-9f);
  }
#pragma unroll
  for (int jt = 0; jt < 4; ++jt)
#pragma unroll
    for (int r = 0; r < 4; ++r)
      a_lds[(wid * 16 + g * 4 + r) * LDA + jt * 16 + c16] = f2bf(acc[jt][r] * s[r]);

  __syncthreads();

  // ---- circuit: [u|v](64x128) = a(64x64) * Mc^T ----
  f32x4 uv[8];
#pragma unroll
  for (int n = 0; n < 8; ++n) uv[n] = f32x4{0.f, 0.f, 0.f, 0.f};
#pragma unroll
  for (int kk = 0; kk < 2; ++kk) {
    bf16x8 af = *(const bf16x8*)(a_lds + (wid * 16 + c16) * LDA + kk * 32 + g * 8);
#pragma unroll
    for (int n = 0; n < 8; ++n) {
      bf16x8 bf_ = *(const bf16x8*)(Mc + (n * 16 + c16) * 64 + kk * 32 + g * 8);
      uv[n] = __builtin_amdgcn_mfma_f32_16x16x32_bf16(af, bf_, uv[n], 0, 0, 0);
    }
  }

  // ---- probs = u^2 + v^2 ----
#pragma unroll
  for (int n = 0; n < 4; ++n)
#pragma unroll
    for (int r = 0; r < 4; ++r) {
      float p = uv[n][r] * uv[n][r] + uv[n + 4][r] * uv[n + 4][r];
      p_lds[(wid * 16 + g * 4 + r) * LDA + n * 16 + c16] = f2bf(p);
    }
  __syncthreads();

  // ---- out(64x64) = probs * Wout^T + b_out ----
  f32x4 o[4];
#pragma unroll
  for (int ot = 0; ot < 4; ++ot) { float bo = b_out[ot * 16 + c16]; o[ot] = f32x4{bo, bo, bo, bo}; }
#pragma unroll
  for (int kk = 0; kk < 2; ++kk) {
    bf16x8 af = *(const bf16x8*)(p_lds + (wid * 16 + c16) * LDA + kk * 32 + g * 8);
#pragma unroll
    for (int ot = 0; ot < 4; ++ot) {
      bf16x8 bf_ = *(const bf16x8*)(Wo + (ot * 16 + c16) * 64 + kk * 32 + g * 8);
      o[ot] = __builtin_amdgcn_mfma_f32_16x16x32_bf16(af, bf_, o[ot], 0, 0, 0);
    }
  }

  __syncthreads();   // everyone done reading a_lds/p_lds before o_lds overwrites them
#pragma unroll
  for (int ot = 0; ot < 4; ++ot)
#pragma unroll
    for (int r = 0; r < 4; ++r)
      o_lds[(ot * 16 + c16) * LDO + wid * 16 + g * 4 + r] = o[ot][r];
  __syncthreads();

  // coalesced store: out[b][o][h][w]
  float* outb = out + (size_t)b * QD * HW * HW + h * HW;
#pragma unroll
  for (int it = 0; it < 16; ++it) {
    int orow = it * 4 + wid;
    outb[orow * (HW * HW) + lane] = o_lds[orow * LDO + lane];
  }
}

extern "C" void kernel_launch(void* const* d_in, const int* in_sizes, int n_in,
                              void* d_out, int out_size, void* d_ws, size_t ws_size,
                              hipStream_t stream) {
  const float* x          = (const float*)d_in[0];
  const float* inp_scale  = (const float*)d_in[1];
  const float* in_proj_w  = (const float*)d_in[2];
  const float* in_proj_b  = (const float*)d_in[3];
  const float* weights    = (const float*)d_in[4];
  const float* meas_w     = (const float*)d_in[5];
  const float* out_proj_w = (const float*)d_in[6];
  const float* out_proj_b = (const float*)d_in[7];
  unsigned short* ws = (unsigned short*)d_ws;

  prep_kernel<<<1, 256, 0, stream>>>(in_proj_w, inp_scale, weights, meas_w, out_proj_w, ws);
  main_kernel<<<NB * HW, 256, 0, stream>>>(x, in_proj_b, out_proj_b, ws, (float*)d_out);
}

// Round 2
// 51.990 us; speedup vs baseline: 1.2911x; 1.2911x over previous
//
#include <hip/hip_runtime.h>

typedef float f32x4 __attribute__((ext_vector_type(4)));
typedef float f32x4v __attribute__((ext_vector_type(4)));
typedef short bf16x8 __attribute__((ext_vector_type(8)));

#define NB   16
#define CIN  32
#define HW   64
#define CKK  288   // = 9*32, K-permuted as k' = pos*32 + cc
#define QD   64

// ws layout (ushort elems): Ws[64][288] @0, Mc[128][64] @36864, Wout[64][64] @45056
#define WS_OFF_MC 36864
#define WS_OFF_WO (36864 + 8192)

__device__ __forceinline__ unsigned short f2bf(float f) {
  unsigned u = __builtin_bit_cast(unsigned, f);
  u += 0x7FFFu + ((u >> 16) & 1u);   // RNE
  return (unsigned short)(u >> 16);
}

struct C2 { float r, i; };
struct M2 { C2 a, b, c, d; };  // [[a,b],[c,d]]

__device__ __forceinline__ C2 cmul(C2 x, C2 y) { return { x.r*y.r - x.i*y.i, x.r*y.i + x.i*y.r }; }
__device__ __forceinline__ C2 cadd(C2 x, C2 y) { return { x.r + y.r, x.i + y.i }; }
__device__ __forceinline__ M2 mmul(M2 X, M2 Y) {  // X*Y (Y applied first)
  return { cadd(cmul(X.a, Y.a), cmul(X.b, Y.c)),
           cadd(cmul(X.a, Y.b), cmul(X.b, Y.d)),
           cadd(cmul(X.c, Y.a), cmul(X.d, Y.c)),
           cadd(cmul(X.c, Y.b), cmul(X.d, Y.d)) };
}

__device__ __forceinline__ M2 mRX(float t) {
  float s, c; __sincosf(t * 0.5f, &s, &c);
  return { {c,0.f}, {0.f,-s}, {0.f,-s}, {c,0.f} };
}
__device__ __forceinline__ M2 mRY(float t) {
  float s, c; __sincosf(t * 0.5f, &s, &c);
  return { {c,0.f}, {-s,0.f}, {s,0.f}, {c,0.f} };
}
__device__ __forceinline__ M2 mU3(float t, float p, float lm) {
  float s, c; __sincosf(t * 0.5f, &s, &c);
  float sp, cp; __sincosf(p, &sp, &cp);
  float sl, cl; __sincosf(lm, &sl, &cl);
  float spl, cpl; __sincosf(p + lm, &spl, &cpl);
  return { {c,0.f}, {-cl*s, -sl*s}, {cp*s, sp*s}, {cpl*c, spl*c} };
}

// 38 blocks x 256: blocks 0-35 convert Ws (K-permuted), 36 converts Wout, 37 runs circuit
__global__ __launch_bounds__(256) void prep_kernel(
    const float* __restrict__ in_proj_w, const float* __restrict__ inp_scale,
    const float* __restrict__ weights, const float* __restrict__ meas_w,
    const float* __restrict__ out_proj_w, unsigned short* __restrict__ ws)
{
  const int tid = threadIdx.x, blk = blockIdx.x;

  if (blk < 36) {
    int e0 = blk * 512 + tid * 2;
#pragma unroll
    for (int u = 0; u < 2; ++u) {
      int e = e0 + u;
      int j = e / CKK, k2 = e - j * CKK;
      int pos = k2 >> 5, cc = k2 & 31;
      int src = cc * 9 + pos;
      ws[e] = f2bf(in_proj_w[j * CKK + src] * inp_scale[src]);
    }
    return;
  }
  if (blk == 36) {
    unsigned short* Wo = ws + WS_OFF_WO;
#pragma unroll
    for (int v = 0; v < 4; ++v) {
      int e = tid * 16 + v * 4;
      f32x4v f = *(const f32x4v*)(out_proj_w + e);
      Wo[e + 0] = f2bf(f[0]); Wo[e + 1] = f2bf(f[1]);
      Wo[e + 2] = f2bf(f[2]); Wo[e + 3] = f2bf(f[3]);
    }
    return;
  }

  const int lane = tid & 63, wid = tid >> 6;
  float wq[36], mq[18];
#pragma unroll
  for (int i = 0; i < 36; ++i) wq[i] = weights[i];
#pragma unroll
  for (int i = 0; i < 18; ++i) mq[i] = meas_w[i];

  float mre[16], mim[16];
#pragma unroll
  for (int j = 0; j < 16; ++j) { mre[j] = (lane == wid * 16 + j) ? 1.f : 0.f; mim[j] = 0.f; }

  auto apply = [&](int bit, M2 U) {
    int rb = (lane >> bit) & 1;
    float arr = rb ? U.d.r : U.a.r, ari = rb ? U.d.i : U.a.i;
    float brr = rb ? U.c.r : U.b.r, bri = rb ? U.c.i : U.b.i;
#pragma unroll
    for (int j = 0; j < 16; ++j) {
      float pre = __shfl_xor(mre[j], 1 << bit);
      float pim = __shfl_xor(mim[j], 1 << bit);
      float nr = arr * mre[j] - ari * mim[j] + brr * pre - bri * pim;
      float ni = arr * mim[j] + ari * mre[j] + brr * pim + bri * pre;
      mre[j] = nr; mim[j] = ni;
    }
  };
  auto cnot = [&](int wire) {
    int cb = 5 - wire, tb = 4 - wire;
    int ctrl = (lane >> cb) & 1;
#pragma unroll
    for (int j = 0; j < 16; ++j) {
      float pre = __shfl_xor(mre[j], 1 << tb);
      float pim = __shfl_xor(mim[j], 1 << tb);
      mre[j] = ctrl ? pre : mre[j];
      mim[j] = ctrl ? pim : mim[j];
    }
  };

  for (int l = 0; l < 2; ++l) {
    for (int q = 0; q < 6; ++q) {
      const float* wp = wq + (l * 6 + q) * 3;
      apply(5 - q, mmul(mRY(wp[1]), mRX(wp[0])));
    }
    for (int q = 0; q < 5; ++q) cnot(q);
    for (int q = 0; q < 6; ++q) {
      const float* wp = wq + (l * 6 + q) * 3;
      M2 g = mRY(wp[2]);
      if (l == 1) {
        const float* mp = mq + q * 3;
        g = mmul(mU3(mp[0], mp[1], mp[2]), g);
      }
      apply(5 - q, g);
    }
  }

  unsigned short* Mc = ws + WS_OFF_MC;
#pragma unroll
  for (int j = 0; j < 16; ++j) {
    int col = wid * 16 + j;
    Mc[lane * 64 + col]        = f2bf(mre[j]);
    Mc[(64 + lane) * 64 + col] = f2bf(mim[j]);
  }
}

#define LDA 72
#define LDO 65

__global__ __launch_bounds__(256) void main_kernel(
    const float* __restrict__ x, const float* __restrict__ b_in,
    const float* __restrict__ b_out, const unsigned short* __restrict__ ws,
    float* __restrict__ out)
{
  __shared__ __align__(16) unsigned char smem[18432];
  unsigned short* a_lds = (unsigned short*)smem;
  unsigned short* p_lds = (unsigned short*)(smem + 9216);
  float* o_lds = (float*)smem;

  const int tid = threadIdx.x, lane = tid & 63, wid = tid >> 6;
  const int g = lane >> 4, c16 = lane & 15;
  const int blk = blockIdx.x;
  const int b = blk >> 6, h = blk & 63;

  const unsigned short* Ws = ws;
  const unsigned short* Mc = ws + WS_OFF_MC;
  const unsigned short* Wo = ws + WS_OFF_WO;

  f32x4 acc[4];
#pragma unroll
  for (int jt = 0; jt < 4; ++jt) { float bi = b_in[jt * 16 + c16]; acc[jt] = f32x4{bi, bi, bi, bi}; }

  const int ar = wid * 16 + c16;
  const float* xb = x + b * CIN * HW * HW;
#pragma unroll
  for (int kk = 0; kk < 9; ++kk) {
    const int di = kk / 3, dj = kk % 3;
    const int y = h + di - 1;
    const int xw = ar + dj - 1;
    const bool ok = ((unsigned)y < 64u) & ((unsigned)xw < 64u);
    const float* px = xb + y * 64 + xw;
    bf16x8 af;
#pragma unroll
    for (int i = 0; i < 8; ++i) {
      int cc = g * 8 + i;
      float v = ok ? px[cc * 4096] : 0.f;
      af[i] = (short)f2bf(v);
    }
#pragma unroll
    for (int jt = 0; jt < 4; ++jt) {
      bf16x8 bf_ = *(const bf16x8*)(Ws + (jt * 16 + c16) * CKK + kk * 32 + g * 8);
      acc[jt] = __builtin_amdgcn_mfma_f32_16x16x32_bf16(af, bf_, acc[jt], 0, 0, 0);
    }
  }

  float s[4];
#pragma unroll
  for (int r = 0; r < 4; ++r) {
    float t = acc[0][r] * acc[0][r] + acc[1][r] * acc[1][r] +
              acc[2][r] * acc[2][r] + acc[3][r] * acc[3][r];
    t += __shfl_xor(t, 1); t += __shfl_xor(t, 2); t += __shfl_xor(t, 4); t += __shfl_xor(t, 8);
    s[r] = 1.f / (sqrtf(t) + 1e-9f);
  }
#pragma unroll
  for (int jt = 0; jt < 4; ++jt)
#pragma unroll
    for (int r = 0; r < 4; ++r)
      a_lds[(wid * 16 + g * 4 + r) * LDA + jt * 16 + c16] = f2bf(acc[jt][r] * s[r]);

  __syncthreads();

  f32x4 uv[8];
#pragma unroll
  for (int n = 0; n < 8; ++n) uv[n] = f32x4{0.f, 0.f, 0.f, 0.f};
#pragma unroll
  for (int kk = 0; kk < 2; ++kk) {
    bf16x8 af = *(const bf16x8*)(a_lds + (wid * 16 + c16) * LDA + kk * 32 + g * 8);
#pragma unroll
    for (int n = 0; n < 8; ++n) {
      bf16x8 bf_ = *(const bf16x8*)(Mc + (n * 16 + c16) * 64 + kk * 32 + g * 8);
      uv[n] = __builtin_amdgcn_mfma_f32_16x16x32_bf16(af, bf_, uv[n], 0, 0, 0);
    }
  }

#pragma unroll
  for (int n = 0; n < 4; ++n)
#pragma unroll
    for (int r = 0; r < 4; ++r) {
      float p = uv[n][r] * uv[n][r] + uv[n + 4][r] * uv[n + 4][r];
      p_lds[(wid * 16 + g * 4 + r) * LDA + n * 16 + c16] = f2bf(p);
    }
  __syncthreads();

  f32x4 o[4];
#pragma unroll
  for (int ot = 0; ot < 4; ++ot) { float bo = b_out[ot * 16 + c16]; o[ot] = f32x4{bo, bo, bo, bo}; }
#pragma unroll
  for (int kk = 0; kk < 2; ++kk) {
    bf16x8 af = *(const bf16x8*)(p_lds + (wid * 16 + c16) * LDA + kk * 32 + g * 8);
#pragma unroll
    for (int ot = 0; ot < 4; ++ot) {
      bf16x8 bf_ = *(const bf16x8*)(Wo + (ot * 16 + c16) * 64 + kk * 32 + g * 8);
      o[ot] = __builtin_amdgcn_mfma_f32_16x16x32_bf16(af, bf_, o[ot], 0, 0, 0);
    }
  }

  __syncthreads();
#pragma unroll
  for (int ot = 0; ot < 4; ++ot)
#pragma unroll
    for (int r = 0; r < 4; ++r)
      o_lds[(ot * 16 + c16) * LDO + wid * 16 + g * 4 + r] = o[ot][r];
  __syncthreads();

  float* outb = out + (size_t)b * QD * HW * HW + h * HW;
#pragma unroll
  for (int it = 0; it < 16; ++it) {
    int orow = it * 4 + wid;
    outb[orow * (HW * HW) + lane] = o_lds[orow * LDO + lane];
  }
}

extern "C" void kernel_launch(void* const* d_in, const int* in_sizes, int n_in,
                              void* d_out, int out_size, void* d_ws, size_t ws_size,
                              hipStream_t stream) {
  const float* x          = (const float*)d_in[0];
  const float* inp_scale  = (const float*)d_in[1];
  const float* in_proj_w  = (const float*)d_in[2];
  const float* in_proj_b  = (const float*)d_in[3];
  const float* weights    = (const float*)d_in[4];
  const float* meas_w     = (const float*)d_in[5];
  const float* out_proj_w = (const float*)d_in[6];
  const float* out_proj_b = (const float*)d_in[7];
  unsigned short* ws = (unsigned short*)d_ws;

  prep_kernel<<<38, 256, 0, stream>>>(in_proj_w, inp_scale, weights, meas_w, out_proj_w, ws);
  main_kernel<<<NB * HW, 256, 0, stream>>>(x, in_proj_b, out_proj_b, ws, (float*)d_out);
}

// Round 3
// 49.296 us; speedup vs baseline: 1.3617x; 1.0546x over previous
//
#include <hip/hip_runtime.h>

typedef float f32x4 __attribute__((ext_vector_type(4)));
typedef float f32x4v __attribute__((ext_vector_type(4)));
typedef short bf16x8 __attribute__((ext_vector_type(8)));

#define NB   16
#define CIN  32
#define HW   64
#define CKK  288   // = 9*32, K-permuted as k' = pos*32 + cc
#define QD   64

// ws layout (ushort elems): Ws[64][288] @0, Mc[128][64] @36864, Wout[64][64] @45056
#define WS_OFF_MC 36864
#define WS_OFF_WO (36864 + 8192)

__device__ __forceinline__ unsigned short f2bf(float f) {
  unsigned u = __builtin_bit_cast(unsigned, f);
  u += 0x7FFFu + ((u >> 16) & 1u);   // RNE
  return (unsigned short)(u >> 16);
}

struct C2 { float r, i; };
struct M2 { C2 a, b, c, d; };  // [[a,b],[c,d]]

__device__ __forceinline__ C2 cmul(C2 x, C2 y) { return { x.r*y.r - x.i*y.i, x.r*y.i + x.i*y.r }; }
__device__ __forceinline__ C2 cadd(C2 x, C2 y) { return { x.r + y.r, x.i + y.i }; }
__device__ __forceinline__ M2 mmul(M2 X, M2 Y) {  // X*Y (Y applied first)
  return { cadd(cmul(X.a, Y.a), cmul(X.b, Y.c)),
           cadd(cmul(X.a, Y.b), cmul(X.b, Y.d)),
           cadd(cmul(X.c, Y.a), cmul(X.d, Y.c)),
           cadd(cmul(X.c, Y.b), cmul(X.d, Y.d)) };
}

__device__ __forceinline__ M2 mRX(float t) {
  float s, c; __sincosf(t * 0.5f, &s, &c);
  return { {c,0.f}, {0.f,-s}, {0.f,-s}, {c,0.f} };
}
__device__ __forceinline__ M2 mRY(float t) {
  float s, c; __sincosf(t * 0.5f, &s, &c);
  return { {c,0.f}, {-s,0.f}, {s,0.f}, {c,0.f} };
}
__device__ __forceinline__ M2 mU3(float t, float p, float lm) {
  float s, c; __sincosf(t * 0.5f, &s, &c);
  float sp, cp; __sincosf(p, &sp, &cp);
  float sl, cl; __sincosf(lm, &sl, &cl);
  float spl, cpl; __sincosf(p + lm, &spl, &cpl);
  return { {c,0.f}, {-cl*s, -sl*s}, {cp*s, sp*s}, {cpl*c, spl*c} };
}

// 38 blocks x 256: blocks 0-35 convert Ws (K-permuted), 36 converts Wout, 37 runs circuit
__global__ __launch_bounds__(256) void prep_kernel(
    const float* __restrict__ in_proj_w, const float* __restrict__ inp_scale,
    const float* __restrict__ weights, const float* __restrict__ meas_w,
    const float* __restrict__ out_proj_w, unsigned short* __restrict__ ws)
{
  const int tid = threadIdx.x, blk = blockIdx.x;

  if (blk < 36) {
    int e0 = blk * 512 + tid * 2;
#pragma unroll
    for (int u = 0; u < 2; ++u) {
      int e = e0 + u;
      int j = e / CKK, k2 = e - j * CKK;
      int pos = k2 >> 5, cc = k2 & 31;
      int src = cc * 9 + pos;
      ws[e] = f2bf(in_proj_w[j * CKK + src] * inp_scale[src]);
    }
    return;
  }
  if (blk == 36) {
    unsigned short* Wo = ws + WS_OFF_WO;
#pragma unroll
    for (int v = 0; v < 4; ++v) {
      int e = tid * 16 + v * 4;
      f32x4v f = *(const f32x4v*)(out_proj_w + e);
      Wo[e + 0] = f2bf(f[0]); Wo[e + 1] = f2bf(f[1]);
      Wo[e + 2] = f2bf(f[2]); Wo[e + 3] = f2bf(f[3]);
    }
    return;
  }

  // ---- circuit block: ALL gate-loop indices must be compile-time so wq/mq
  // stay in VGPRs (runtime-indexed private arrays spill to scratch, rule #20).
  const int lane = tid & 63, wid = tid >> 6;
  float wq[36], mq[18];
#pragma unroll
  for (int i = 0; i < 36; ++i) wq[i] = weights[i];
#pragma unroll
  for (int i = 0; i < 18; ++i) mq[i] = meas_w[i];

  float mre[16], mim[16];
#pragma unroll
  for (int j = 0; j < 16; ++j) { mre[j] = (lane == wid * 16 + j) ? 1.f : 0.f; mim[j] = 0.f; }

  auto apply = [&](int bit, M2 U) {
    int rb = (lane >> bit) & 1;
    float arr = rb ? U.d.r : U.a.r, ari = rb ? U.d.i : U.a.i;
    float brr = rb ? U.c.r : U.b.r, bri = rb ? U.c.i : U.b.i;
#pragma unroll
    for (int j = 0; j < 16; ++j) {
      float pre = __shfl_xor(mre[j], 1 << bit);
      float pim = __shfl_xor(mim[j], 1 << bit);
      float nr = arr * mre[j] - ari * mim[j] + brr * pre - bri * pim;
      float ni = arr * mim[j] + ari * mre[j] + brr * pim + bri * pre;
      mre[j] = nr; mim[j] = ni;
    }
  };
  auto cnot = [&](int wire) {
    int cb = 5 - wire, tb = 4 - wire;
    int ctrl = (lane >> cb) & 1;
#pragma unroll
    for (int j = 0; j < 16; ++j) {
      float pre = __shfl_xor(mre[j], 1 << tb);
      float pim = __shfl_xor(mim[j], 1 << tb);
      mre[j] = ctrl ? pre : mre[j];
      mim[j] = ctrl ? pim : mim[j];
    }
  };

#pragma unroll
  for (int l = 0; l < 2; ++l) {
#pragma unroll
    for (int q = 0; q < 6; ++q) {
      const float* wp = wq + (l * 6 + q) * 3;
      apply(5 - q, mmul(mRY(wp[1]), mRX(wp[0])));
    }
#pragma unroll
    for (int q = 0; q < 5; ++q) cnot(q);
#pragma unroll
    for (int q = 0; q < 6; ++q) {
      const float* wp = wq + (l * 6 + q) * 3;
      M2 g = mRY(wp[2]);
      if (l == 1) {
        const float* mp = mq + q * 3;
        g = mmul(mU3(mp[0], mp[1], mp[2]), g);
      }
      apply(5 - q, g);
    }
  }

  unsigned short* Mc = ws + WS_OFF_MC;
#pragma unroll
  for (int j = 0; j < 16; ++j) {
    int col = wid * 16 + j;
    Mc[lane * 64 + col]        = f2bf(mre[j]);
    Mc[(64 + lane) * 64 + col] = f2bf(mim[j]);
  }
}

#define LDA 72
#define LDO 65

__global__ __launch_bounds__(256) void main_kernel(
    const float* __restrict__ x, const float* __restrict__ b_in,
    const float* __restrict__ b_out, const unsigned short* __restrict__ ws,
    float* __restrict__ out)
{
  __shared__ __align__(16) unsigned char smem[18432];
  unsigned short* a_lds = (unsigned short*)smem;
  unsigned short* p_lds = (unsigned short*)(smem + 9216);
  float* o_lds = (float*)smem;

  const int tid = threadIdx.x, lane = tid & 63, wid = tid >> 6;
  const int g = lane >> 4, c16 = lane & 15;
  const int blk = blockIdx.x;
  const int b = blk >> 6, h = blk & 63;

  const unsigned short* Ws = ws;
  const unsigned short* Mc = ws + WS_OFF_MC;
  const unsigned short* Wo = ws + WS_OFF_WO;

  f32x4 acc[4];
#pragma unroll
  for (int jt = 0; jt < 4; ++jt) { float bi = b_in[jt * 16 + c16]; acc[jt] = f32x4{bi, bi, bi, bi}; }

  const int ar = wid * 16 + c16;
  const float* xb = x + b * CIN * HW * HW;
#pragma unroll
  for (int kk = 0; kk < 9; ++kk) {
    const int di = kk / 3, dj = kk % 3;
    const int y = h + di - 1;
    const int xw = ar + dj - 1;
    const bool ok = ((unsigned)y < 64u) & ((unsigned)xw < 64u);
    const float* px = xb + y * 64 + xw;
    bf16x8 af;
#pragma unroll
    for (int i = 0; i < 8; ++i) {
      int cc = g * 8 + i;
      float v = ok ? px[cc * 4096] : 0.f;
      af[i] = (short)f2bf(v);
    }
#pragma unroll
    for (int jt = 0; jt < 4; ++jt) {
      bf16x8 bf_ = *(const bf16x8*)(Ws + (jt * 16 + c16) * CKK + kk * 32 + g * 8);
      acc[jt] = __builtin_amdgcn_mfma_f32_16x16x32_bf16(af, bf_, acc[jt], 0, 0, 0);
    }
  }

  float s[4];
#pragma unroll
  for (int r = 0; r < 4; ++r) {
    float t = acc[0][r] * acc[0][r] + acc[1][r] * acc[1][r] +
              acc[2][r] * acc[2][r] + acc[3][r] * acc[3][r];
    t += __shfl_xor(t, 1); t += __shfl_xor(t, 2); t += __shfl_xor(t, 4); t += __shfl_xor(t, 8);
    s[r] = 1.f / (sqrtf(t) + 1e-9f);
  }
#pragma unroll
  for (int jt = 0; jt < 4; ++jt)
#pragma unroll
    for (int r = 0; r < 4; ++r)
      a_lds[(wid * 16 + g * 4 + r) * LDA + jt * 16 + c16] = f2bf(acc[jt][r] * s[r]);

  __syncthreads();

  f32x4 uv[8];
#pragma unroll
  for (int n = 0; n < 8; ++n) uv[n] = f32x4{0.f, 0.f, 0.f, 0.f};
#pragma unroll
  for (int kk = 0; kk < 2; ++kk) {
    bf16x8 af = *(const bf16x8*)(a_lds + (wid * 16 + c16) * LDA + kk * 32 + g * 8);
#pragma unroll
    for (int n = 0; n < 8; ++n) {
      bf16x8 bf_ = *(const bf16x8*)(Mc + (n * 16 + c16) * 64 + kk * 32 + g * 8);
      uv[n] = __builtin_amdgcn_mfma_f32_16x16x32_bf16(af, bf_, uv[n], 0, 0, 0);
    }
  }

#pragma unroll
  for (int n = 0; n < 4; ++n)
#pragma unroll
    for (int r = 0; r < 4; ++r) {
      float p = uv[n][r] * uv[n][r] + uv[n + 4][r] * uv[n + 4][r];
      p_lds[(wid * 16 + g * 4 + r) * LDA + n * 16 + c16] = f2bf(p);
    }
  __syncthreads();

  f32x4 o[4];
#pragma unroll
  for (int ot = 0; ot < 4; ++ot) { float bo = b_out[ot * 16 + c16]; o[ot] = f32x4{bo, bo, bo, bo}; }
#pragma unroll
  for (int kk = 0; kk < 2; ++kk) {
    bf16x8 af = *(const bf16x8*)(p_lds + (wid * 16 + c16) * LDA + kk * 32 + g * 8);
#pragma unroll
    for (int ot = 0; ot < 4; ++ot) {
      bf16x8 bf_ = *(const bf16x8*)(Wo + (ot * 16 + c16) * 64 + kk * 32 + g * 8);
      o[ot] = __builtin_amdgcn_mfma_f32_16x16x32_bf16(af, bf_, o[ot], 0, 0, 0);
    }
  }

  __syncthreads();
#pragma unroll
  for (int ot = 0; ot < 4; ++ot)
#pragma unroll
    for (int r = 0; r < 4; ++r)
      o_lds[(ot * 16 + c16) * LDO + wid * 16 + g * 4 + r] = o[ot][r];
  __syncthreads();

  float* outb = out + (size_t)b * QD * HW * HW + h * HW;
#pragma unroll
  for (int it = 0; it < 16; ++it) {
    int orow = it * 4 + wid;
    outb[orow * (HW * HW) + lane] = o_lds[orow * LDO + lane];
  }
}

extern "C" void kernel_launch(void* const* d_in, const int* in_sizes, int n_in,
                              void* d_out, int out_size, void* d_ws, size_t ws_size,
                              hipStream_t stream) {
  const float* x          = (const float*)d_in[0];
  const float* inp_scale  = (const float*)d_in[1];
  const float* in_proj_w  = (const float*)d_in[2];
  const float* in_proj_b  = (const float*)d_in[3];
  const float* weights    = (const float*)d_in[4];
  const float* meas_w     = (const float*)d_in[5];
  const float* out_proj_w = (const float*)d_in[6];
  const float* out_proj_b = (const float*)d_in[7];
  unsigned short* ws = (unsigned short*)d_ws;

  prep_kernel<<<38, 256, 0, stream>>>(in_proj_w, inp_scale, weights, meas_w, out_proj_w, ws);
  main_kernel<<<NB * HW, 256, 0, stream>>>(x, in_proj_b, out_proj_b, ws, (float*)d_out);
}

// Round 4
// 42.230 us; speedup vs baseline: 1.5895x; 1.1673x over previous
//
#include <hip/hip_runtime.h>

typedef float f32x4 __attribute__((ext_vector_type(4)));
typedef float f32x4v __attribute__((ext_vector_type(4)));
typedef short bf16x8 __attribute__((ext_vector_type(8)));

#define NB   16
#define CIN  32
#define HW   64
#define CKK  288   // = 9*32, K-permuted as k' = pos*32 + cc
#define QD   64

// ws layout (ushort elems): Ws[64][288] @0, Mc[128][64] @36864, Wout[64][64] @45056
#define WS_OFF_MC 36864
#define WS_OFF_WO (36864 + 8192)

__device__ __forceinline__ unsigned short f2bf(float f) {
  unsigned u = __builtin_bit_cast(unsigned, f);
  u += 0x7FFFu + ((u >> 16) & 1u);   // RNE
  return (unsigned short)(u >> 16);
}

struct C2 { float r, i; };
struct M2 { C2 a, b, c, d; };  // [[a,b],[c,d]]

__device__ __forceinline__ C2 cmul(C2 x, C2 y) { return { x.r*y.r - x.i*y.i, x.r*y.i + x.i*y.r }; }
__device__ __forceinline__ C2 cadd(C2 x, C2 y) { return { x.r + y.r, x.i + y.i }; }
__device__ __forceinline__ M2 mmul(M2 X, M2 Y) {  // X*Y (Y applied first)
  return { cadd(cmul(X.a, Y.a), cmul(X.b, Y.c)),
           cadd(cmul(X.a, Y.b), cmul(X.b, Y.d)),
           cadd(cmul(X.c, Y.a), cmul(X.d, Y.c)),
           cadd(cmul(X.c, Y.b), cmul(X.d, Y.d)) };
}

__device__ __forceinline__ M2 mRX(float t) {
  float s, c; __sincosf(t * 0.5f, &s, &c);
  return { {c,0.f}, {0.f,-s}, {0.f,-s}, {c,0.f} };
}
__device__ __forceinline__ M2 mRY(float t) {
  float s, c; __sincosf(t * 0.5f, &s, &c);
  return { {c,0.f}, {-s,0.f}, {s,0.f}, {c,0.f} };
}
__device__ __forceinline__ M2 mU3(float t, float p, float lm) {
  float s, c; __sincosf(t * 0.5f, &s, &c);
  float sp, cp; __sincosf(p, &sp, &cp);
  float sl, cl; __sincosf(lm, &sl, &cl);
  float spl, cpl; __sincosf(p + lm, &spl, &cpl);
  return { {c,0.f}, {-cl*s, -sl*s}, {cp*s, sp*s}, {cpl*c, spl*c} };
}

// 38 blocks x 256: blocks 0-35 convert Ws (K-permuted), 36 converts Wout, 37 runs circuit
__global__ __launch_bounds__(256) void prep_kernel(
    const float* __restrict__ in_proj_w, const float* __restrict__ inp_scale,
    const float* __restrict__ weights, const float* __restrict__ meas_w,
    const float* __restrict__ out_proj_w, unsigned short* __restrict__ ws)
{
  const int tid = threadIdx.x, blk = blockIdx.x;

  if (blk < 36) {
    int e0 = blk * 512 + tid * 2;
#pragma unroll
    for (int u = 0; u < 2; ++u) {
      int e = e0 + u;
      int j = e / CKK, k2 = e - j * CKK;
      int pos = k2 >> 5, cc = k2 & 31;
      int src = cc * 9 + pos;
      ws[e] = f2bf(in_proj_w[j * CKK + src] * inp_scale[src]);
    }
    return;
  }
  if (blk == 36) {
    unsigned short* Wo = ws + WS_OFF_WO;
#pragma unroll
    for (int v = 0; v < 4; ++v) {
      int e = tid * 16 + v * 4;
      f32x4v f = *(const f32x4v*)(out_proj_w + e);
      Wo[e + 0] = f2bf(f[0]); Wo[e + 1] = f2bf(f[1]);
      Wo[e + 2] = f2bf(f[2]); Wo[e + 3] = f2bf(f[3]);
    }
    return;
  }

  // ======== circuit block ========
  // Shuffle-minimized: (1) first-layer RX*RY on identity = tensor product,
  // computed in-register (0 shuffles); (2) CNOT chains tracked lazily as
  // GF2-linear layout maps (T after chain1, T^2 after chain2) -> CNOTs are
  // free; later gates shuffle by constant masks sigma^-1(e_b) and select
  // coefficients by the true state bit; (3) layer-0 trailing RY merged with
  // layer-1 RX*RY (no CNOT between). 34 shuffle-applies -> 12.
  const int lane = tid & 63, wid = tid >> 6;

  float wq[36], mq[18];
#pragma unroll
  for (int i = 0; i < 36; ++i) wq[i] = weights[i];
#pragma unroll
  for (int i = 0; i < 18; ++i) mq[i] = meas_w[i];

  // gate matrices (all loop indices compile-time)
  M2 G0[6], G1[6], G2[6];
#pragma unroll
  for (int q = 0; q < 6; ++q) {
    // layer0 RX then RY
    G0[q] = mmul(mRY(wq[q * 3 + 1]), mRX(wq[q * 3 + 0]));
    // layer0 trailing RY, then layer1 RX, then layer1 RY
    G1[q] = mmul(mmul(mRY(wq[18 + q * 3 + 1]), mRX(wq[18 + q * 3 + 0])), mRY(wq[q * 3 + 2]));
    // layer1 trailing RY, then measurement U3
    G2[q] = mmul(mU3(mq[q * 3], mq[q * 3 + 1], mq[q * 3 + 2]), mRY(wq[18 + q * 3 + 2]));
  }

  // ---- init: tensor product of G0 over the 6 qubits (state = lane, col = wid*16+j)
  const int s5 = (lane >> 5) & 1, s4 = (lane >> 4) & 1, s3 = (lane >> 3) & 1;
  const int s2 = (lane >> 2) & 1, s1 = (lane >> 1) & 1, s0 = lane & 1;
  const int w1 = (wid >> 1) & 1, w0 = wid & 1;   // col bits 5,4

  // row-selected entries: Gq[s][0], Gq[s][1]
  C2 e0q0 = s5 ? G0[0].c : G0[0].a, e1q0 = s5 ? G0[0].d : G0[0].b;
  C2 e0q1 = s4 ? G0[1].c : G0[1].a, e1q1 = s4 ? G0[1].d : G0[1].b;
  C2 e0q2 = s3 ? G0[2].c : G0[2].a, e1q2 = s3 ? G0[2].d : G0[2].b;
  C2 e0q3 = s2 ? G0[3].c : G0[3].a, e1q3 = s2 ? G0[3].d : G0[3].b;
  C2 e0q4 = s1 ? G0[4].c : G0[4].a, e1q4 = s1 ? G0[4].d : G0[4].b;
  C2 e0q5 = s0 ? G0[5].c : G0[5].a, e1q5 = s0 ? G0[5].d : G0[5].b;

  C2 f0 = w1 ? e1q0 : e0q0;       // col bit5 (wave-uniform)
  C2 f1 = w0 ? e1q1 : e0q1;       // col bit4
  C2 P01 = cmul(f0, f1);

  float mre[16], mim[16];
  {
    C2 A0 = cmul(P01, e0q2), A1 = cmul(P01, e1q2);                 // col bit3
    C2 B00 = cmul(A0, e0q3), B01 = cmul(A0, e1q3);                 // col bit2
    C2 B10 = cmul(A1, e0q3), B11 = cmul(A1, e1q3);
    C2 Cs[8];
    Cs[0] = cmul(B00, e0q4); Cs[1] = cmul(B00, e1q4);              // col bit1
    Cs[2] = cmul(B01, e0q4); Cs[3] = cmul(B01, e1q4);
    Cs[4] = cmul(B10, e0q4); Cs[5] = cmul(B10, e1q4);
    Cs[6] = cmul(B11, e0q4); Cs[7] = cmul(B11, e1q4);
#pragma unroll
    for (int h = 0; h < 8; ++h) {
      // j = (bit3<<3)|(bit2<<2)|(bit1<<1)|bit0 ; Cs index h = (b3<<2)|(b2<<1)|b1
      C2 lo = cmul(Cs[h], e0q5), hi = cmul(Cs[h], e1q5);           // col bit0
      int j = h * 2;
      mre[j] = lo.r; mim[j] = lo.i;
      mre[j + 1] = hi.r; mim[j + 1] = hi.i;
    }
  }

  // layout maps: t1 = T(lane), t2 = T^2(lane)
  const int t1 = (lane ^ (lane >> 1) ^ (lane >> 2) ^ (lane >> 3) ^ (lane >> 4) ^ (lane >> 5)) & 63;
  const int t2 = (lane ^ (lane >> 2) ^ (lane >> 4)) & 63;

  auto applyM = [&](int maskShuf, int rb, M2 U) {
    float arr = rb ? U.d.r : U.a.r, ari = rb ? U.d.i : U.a.i;   // coeff on own value
    float brr = rb ? U.c.r : U.b.r, bri = rb ? U.c.i : U.b.i;   // coeff on partner
#pragma unroll
    for (int j = 0; j < 16; ++j) {
      float pre = __shfl_xor(mre[j], maskShuf);
      float pim = __shfl_xor(mim[j], maskShuf);
      float nr = arr * mre[j] - ari * mim[j] + brr * pre - bri * pim;
      float ni = arr * mim[j] + ari * mre[j] + brr * pim + bri * pre;
      mre[j] = nr; mim[j] = ni;
    }
  };

  // sigma1^-1(e_b) = e_b | e_{b-1};  sigma2^-1(e_b) = e_b ^ e_{b-2}
  const int MK1[6] = {0x01, 0x03, 0x06, 0x0C, 0x18, 0x30};
  const int MK2[6] = {0x01, 0x02, 0x05, 0x0A, 0x14, 0x28};

#pragma unroll
  for (int q = 0; q < 6; ++q) {
    const int b = 5 - q;
    applyM(MK1[b], (t1 >> b) & 1, G1[q]);
  }
#pragma unroll
  for (int q = 0; q < 6; ++q) {
    const int b = 5 - q;
    applyM(MK2[b], (t2 >> b) & 1, G2[q]);
  }

  // lane holds state T^2(lane) -> scatter rows by t2
  unsigned short* Mc = ws + WS_OFF_MC;
#pragma unroll
  for (int j = 0; j < 16; ++j) {
    int col = wid * 16 + j;
    Mc[t2 * 64 + col]        = f2bf(mre[j]);
    Mc[(64 + t2) * 64 + col] = f2bf(mim[j]);
  }
}

#define LDA 72
#define LDO 65

__global__ __launch_bounds__(256) void main_kernel(
    const float* __restrict__ x, const float* __restrict__ b_in,
    const float* __restrict__ b_out, const unsigned short* __restrict__ ws,
    float* __restrict__ out)
{
  __shared__ __align__(16) unsigned char smem[18432];
  unsigned short* a_lds = (unsigned short*)smem;
  unsigned short* p_lds = (unsigned short*)(smem + 9216);
  float* o_lds = (float*)smem;

  const int tid = threadIdx.x, lane = tid & 63, wid = tid >> 6;
  const int g = lane >> 4, c16 = lane & 15;
  const int blk = blockIdx.x;
  const int b = blk >> 6, h = blk & 63;

  const unsigned short* Ws = ws;
  const unsigned short* Mc = ws + WS_OFF_MC;
  const unsigned short* Wo = ws + WS_OFF_WO;

  f32x4 acc[4];
#pragma unroll
  for (int jt = 0; jt < 4; ++jt) { float bi = b_in[jt * 16 + c16]; acc[jt] = f32x4{bi, bi, bi, bi}; }

  const int ar = wid * 16 + c16;
  const float* xb = x + b * CIN * HW * HW;
#pragma unroll
  for (int kk = 0; kk < 9; ++kk) {
    const int di = kk / 3, dj = kk % 3;
    const int y = h + di - 1;
    const int xw = ar + dj - 1;
    const bool ok = ((unsigned)y < 64u) & ((unsigned)xw < 64u);
    const float* px = xb + y * 64 + xw;
    bf16x8 af;
#pragma unroll
    for (int i = 0; i < 8; ++i) {
      int cc = g * 8 + i;
      float v = ok ? px[cc * 4096] : 0.f;
      af[i] = (short)f2bf(v);
    }
#pragma unroll
    for (int jt = 0; jt < 4; ++jt) {
      bf16x8 bf_ = *(const bf16x8*)(Ws + (jt * 16 + c16) * CKK + kk * 32 + g * 8);
      acc[jt] = __builtin_amdgcn_mfma_f32_16x16x32_bf16(af, bf_, acc[jt], 0, 0, 0);
    }
  }

  float s[4];
#pragma unroll
  for (int r = 0; r < 4; ++r) {
    float t = acc[0][r] * acc[0][r] + acc[1][r] * acc[1][r] +
              acc[2][r] * acc[2][r] + acc[3][r] * acc[3][r];
    t += __shfl_xor(t, 1); t += __shfl_xor(t, 2); t += __shfl_xor(t, 4); t += __shfl_xor(t, 8);
    s[r] = 1.f / (sqrtf(t) + 1e-9f);
  }
#pragma unroll
  for (int jt = 0; jt < 4; ++jt)
#pragma unroll
    for (int r = 0; r < 4; ++r)
      a_lds[(wid * 16 + g * 4 + r) * LDA + jt * 16 + c16] = f2bf(acc[jt][r] * s[r]);

  __syncthreads();

  f32x4 uv[8];
#pragma unroll
  for (int n = 0; n < 8; ++n) uv[n] = f32x4{0.f, 0.f, 0.f, 0.f};
#pragma unroll
  for (int kk = 0; kk < 2; ++kk) {
    bf16x8 af = *(const bf16x8*)(a_lds + (wid * 16 + c16) * LDA + kk * 32 + g * 8);
#pragma unroll
    for (int n = 0; n < 8; ++n) {
      bf16x8 bf_ = *(const bf16x8*)(Mc + (n * 16 + c16) * 64 + kk * 32 + g * 8);
      uv[n] = __builtin_amdgcn_mfma_f32_16x16x32_bf16(af, bf_, uv[n], 0, 0, 0);
    }
  }

#pragma unroll
  for (int n = 0; n < 4; ++n)
#pragma unroll
    for (int r = 0; r < 4; ++r) {
      float p = uv[n][r] * uv[n][r] + uv[n + 4][r] * uv[n + 4][r];
      p_lds[(wid * 16 + g * 4 + r) * LDA + n * 16 + c16] = f2bf(p);
    }
  __syncthreads();

  f32x4 o[4];
#pragma unroll
  for (int ot = 0; ot < 4; ++ot) { float bo = b_out[ot * 16 + c16]; o[ot] = f32x4{bo, bo, bo, bo}; }
#pragma unroll
  for (int kk = 0; kk < 2; ++kk) {
    bf16x8 af = *(const bf16x8*)(p_lds + (wid * 16 + c16) * LDA + kk * 32 + g * 8);
#pragma unroll
    for (int ot = 0; ot < 4; ++ot) {
      bf16x8 bf_ = *(const bf16x8*)(Wo + (ot * 16 + c16) * 64 + kk * 32 + g * 8);
      o[ot] = __builtin_amdgcn_mfma_f32_16x16x32_bf16(af, bf_, o[ot], 0, 0, 0);
    }
  }

  __syncthreads();
#pragma unroll
  for (int ot = 0; ot < 4; ++ot)
#pragma unroll
    for (int r = 0; r < 4; ++r)
      o_lds[(ot * 16 + c16) * LDO + wid * 16 + g * 4 + r] = o[ot][r];
  __syncthreads();

  float* outb = out + (size_t)b * QD * HW * HW + h * HW;
#pragma unroll
  for (int it = 0; it < 16; ++it) {
    int orow = it * 4 + wid;
    outb[orow * (HW * HW) + lane] = o_lds[orow * LDO + lane];
  }
}

extern "C" void kernel_launch(void* const* d_in, const int* in_sizes, int n_in,
                              void* d_out, int out_size, void* d_ws, size_t ws_size,
                              hipStream_t stream) {
  const float* x          = (const float*)d_in[0];
  const float* inp_scale  = (const float*)d_in[1];
  const float* in_proj_w  = (const float*)d_in[2];
  const float* in_proj_b  = (const float*)d_in[3];
  const float* weights    = (const float*)d_in[4];
  const float* meas_w     = (const float*)d_in[5];
  const float* out_proj_w = (const float*)d_in[6];
  const float* out_proj_b = (const float*)d_in[7];
  unsigned short* ws = (unsigned short*)d_ws;

  prep_kernel<<<38, 256, 0, stream>>>(in_proj_w, inp_scale, weights, meas_w, out_proj_w, ws);
  main_kernel<<<NB * HW, 256, 0, stream>>>(x, in_proj_b, out_proj_b, ws, (float*)d_out);
}

// Round 5
// 37.479 us; speedup vs baseline: 1.7910x; 1.1268x over previous
//
#include <hip/hip_runtime.h>

typedef float f32x4 __attribute__((ext_vector_type(4)));
typedef float f32x4v __attribute__((ext_vector_type(4)));
typedef short bf16x8 __attribute__((ext_vector_type(8)));

#define NB   16
#define CIN  32
#define HW   64
#define CKK  288
#define QD   64

// ws layout (ushort elems), ALL weight tensors in MFMA fragment-major order:
//   frag f stored as [f][lane(0..63)][8 elems] -> lane reads base + lane*8 (16B, coalesced)
#define WS_WSF 0          // GEMM1 B: 36 frags (kk*4+jt)           -> 18432
#define WS_MCF 18432      // GEMM2 B: 16 frags (kk*8+n), n<4 Re, n>=4 Im -> 8192
#define WS_WOF 26624      // GEMM3 B: 8 frags (kk*4+ot)            -> 4096
#define WS_XBF 30720      // x converted to bf16, same [b][c][y][x] layout -> 2097152

__device__ __forceinline__ unsigned short f2bf(float f) {
  unsigned u = __builtin_bit_cast(unsigned, f);
  u += 0x7FFFu + ((u >> 16) & 1u);   // RNE
  return (unsigned short)(u >> 16);
}

struct C2 { float r, i; };
struct M2 { C2 a, b, c, d; };  // [[a,b],[c,d]]

__device__ __forceinline__ C2 cmul(C2 x, C2 y) { return { x.r*y.r - x.i*y.i, x.r*y.i + x.i*y.r }; }
__device__ __forceinline__ C2 cadd(C2 x, C2 y) { return { x.r + y.r, x.i + y.i }; }
__device__ __forceinline__ M2 mmul(M2 X, M2 Y) {  // X*Y (Y applied first)
  return { cadd(cmul(X.a, Y.a), cmul(X.b, Y.c)),
           cadd(cmul(X.a, Y.b), cmul(X.b, Y.d)),
           cadd(cmul(X.c, Y.a), cmul(X.d, Y.c)),
           cadd(cmul(X.c, Y.b), cmul(X.d, Y.d)) };
}

__device__ __forceinline__ M2 mRX(float t) {
  float s, c; __sincosf(t * 0.5f, &s, &c);
  return { {c,0.f}, {0.f,-s}, {0.f,-s}, {c,0.f} };
}
__device__ __forceinline__ M2 mRY(float t) {
  float s, c; __sincosf(t * 0.5f, &s, &c);
  return { {c,0.f}, {-s,0.f}, {s,0.f}, {c,0.f} };
}
__device__ __forceinline__ M2 mU3(float t, float p, float lm) {
  float s, c; __sincosf(t * 0.5f, &s, &c);
  float sp, cp; __sincosf(p, &sp, &cp);
  float sl, cl; __sincosf(lm, &sl, &cl);
  float spl, cpl; __sincosf(p + lm, &spl, &cpl);
  return { {c,0.f}, {-cl*s, -sl*s}, {cp*s, sp*s}, {cpl*c, spl*c} };
}

// grid = 1062: [0,1024) x->bf16, [1024,1060) WsF, 1060 WoF, 1061 circuit->McF
__global__ __launch_bounds__(256) void prep_kernel(
    const float* __restrict__ x,
    const float* __restrict__ in_proj_w, const float* __restrict__ inp_scale,
    const float* __restrict__ weights, const float* __restrict__ meas_w,
    const float* __restrict__ out_proj_w, unsigned short* __restrict__ ws)
{
  const int tid = threadIdx.x, blk = blockIdx.x;

  if (blk < 1024) {                      // x -> bf16 (coalesced, 8/thread)
    int e0 = blk * 2048 + tid * 8;
    f32x4v a = *(const f32x4v*)(x + e0);
    f32x4v b2 = *(const f32x4v*)(x + e0 + 4);
    bf16x8 o8;
    o8[0] = (short)f2bf(a[0]);  o8[1] = (short)f2bf(a[1]);
    o8[2] = (short)f2bf(a[2]);  o8[3] = (short)f2bf(a[3]);
    o8[4] = (short)f2bf(b2[0]); o8[5] = (short)f2bf(b2[1]);
    o8[6] = (short)f2bf(b2[2]); o8[7] = (short)f2bf(b2[3]);
    *(bf16x8*)(ws + WS_XBF + e0) = o8;
    return;
  }
  if (blk < 1060) {                      // WsF: frag f = kk*4+jt, 512 ushorts
    int f = blk - 1024, kk = f >> 2, jt = f & 3;
#pragma unroll
    for (int u = 0; u < 2; ++u) {
      int r = tid * 2 + u;
      int lw = r >> 3, e = r & 7;
      int row = jt * 16 + (lw & 15);
      int ch = (lw >> 4) * 8 + e;        // patch channel index (0..31)
      int src = ch * 9 + kk;             // original k = c*9 + pos, pos = kk
      ws[WS_WSF + f * 512 + r] = f2bf(in_proj_w[row * CKK + src] * inp_scale[src]);
    }
    return;
  }
  if (blk == 1060) {                     // WoF: 8 frags x 512
#pragma unroll
    for (int m = 0; m < 16; ++m) {
      int d = tid * 16 + m;
      int f = d >> 9, r = d & 511;
      int lw = r >> 3, e = r & 7;
      int kk = f >> 2, ot = f & 3;
      int src = (ot * 16 + (lw & 15)) * 64 + kk * 32 + (lw >> 4) * 8 + e;
      ws[WS_WOF + d] = f2bf(out_proj_w[src]);
    }
    return;
  }

  // ======== circuit block (shuffle-minimized, validated round 4) ========
  const int lane = tid & 63, wid = tid >> 6;

  float wq[36], mq[18];
#pragma unroll
  for (int i = 0; i < 36; ++i) wq[i] = weights[i];
#pragma unroll
  for (int i = 0; i < 18; ++i) mq[i] = meas_w[i];

  M2 G0[6], G1[6], G2[6];
#pragma unroll
  for (int q = 0; q < 6; ++q) {
    G0[q] = mmul(mRY(wq[q * 3 + 1]), mRX(wq[q * 3 + 0]));
    G1[q] = mmul(mmul(mRY(wq[18 + q * 3 + 1]), mRX(wq[18 + q * 3 + 0])), mRY(wq[q * 3 + 2]));
    G2[q] = mmul(mU3(mq[q * 3], mq[q * 3 + 1], mq[q * 3 + 2]), mRY(wq[18 + q * 3 + 2]));
  }

  const int s5 = (lane >> 5) & 1, s4 = (lane >> 4) & 1, s3 = (lane >> 3) & 1;
  const int s2 = (lane >> 2) & 1, s1 = (lane >> 1) & 1, s0 = lane & 1;
  const int w1 = (wid >> 1) & 1, w0 = wid & 1;

  C2 e0q0 = s5 ? G0[0].c : G0[0].a, e1q0 = s5 ? G0[0].d : G0[0].b;
  C2 e0q1 = s4 ? G0[1].c : G0[1].a, e1q1 = s4 ? G0[1].d : G0[1].b;
  C2 e0q2 = s3 ? G0[2].c : G0[2].a, e1q2 = s3 ? G0[2].d : G0[2].b;
  C2 e0q3 = s2 ? G0[3].c : G0[3].a, e1q3 = s2 ? G0[3].d : G0[3].b;
  C2 e0q4 = s1 ? G0[4].c : G0[4].a, e1q4 = s1 ? G0[4].d : G0[4].b;
  C2 e0q5 = s0 ? G0[5].c : G0[5].a, e1q5 = s0 ? G0[5].d : G0[5].b;

  C2 f0 = w1 ? e1q0 : e0q0;
  C2 f1 = w0 ? e1q1 : e0q1;
  C2 P01 = cmul(f0, f1);

  float mre[16], mim[16];
  {
    C2 A0 = cmul(P01, e0q2), A1 = cmul(P01, e1q2);
    C2 B00 = cmul(A0, e0q3), B01 = cmul(A0, e1q3);
    C2 B10 = cmul(A1, e0q3), B11 = cmul(A1, e1q3);
    C2 Cs[8];
    Cs[0] = cmul(B00, e0q4); Cs[1] = cmul(B00, e1q4);
    Cs[2] = cmul(B01, e0q4); Cs[3] = cmul(B01, e1q4);
    Cs[4] = cmul(B10, e0q4); Cs[5] = cmul(B10, e1q4);
    Cs[6] = cmul(B11, e0q4); Cs[7] = cmul(B11, e1q4);
#pragma unroll
    for (int h = 0; h < 8; ++h) {
      C2 lo = cmul(Cs[h], e0q5), hi = cmul(Cs[h], e1q5);
      int j = h * 2;
      mre[j] = lo.r; mim[j] = lo.i;
      mre[j + 1] = hi.r; mim[j + 1] = hi.i;
    }
  }

  const int t1 = (lane ^ (lane >> 1) ^ (lane >> 2) ^ (lane >> 3) ^ (lane >> 4) ^ (lane >> 5)) & 63;
  const int t2 = (lane ^ (lane >> 2) ^ (lane >> 4)) & 63;

  auto applyM = [&](int maskShuf, int rb, M2 U) {
    float arr = rb ? U.d.r : U.a.r, ari = rb ? U.d.i : U.a.i;
    float brr = rb ? U.c.r : U.b.r, bri = rb ? U.c.i : U.b.i;
#pragma unroll
    for (int j = 0; j < 16; ++j) {
      float pre = __shfl_xor(mre[j], maskShuf);
      float pim = __shfl_xor(mim[j], maskShuf);
      float nr = arr * mre[j] - ari * mim[j] + brr * pre - bri * pim;
      float ni = arr * mim[j] + ari * mre[j] + brr * pim + bri * pre;
      mre[j] = nr; mim[j] = ni;
    }
  };

  const int MK1[6] = {0x01, 0x03, 0x06, 0x0C, 0x18, 0x30};
  const int MK2[6] = {0x01, 0x02, 0x05, 0x0A, 0x14, 0x28};

#pragma unroll
  for (int q = 0; q < 6; ++q) { const int b = 5 - q; applyM(MK1[b], (t1 >> b) & 1, G1[q]); }
#pragma unroll
  for (int q = 0; q < 6; ++q) { const int b = 5 - q; applyM(MK2[b], (t2 >> b) & 1, G2[q]); }

  // scatter into fragment-major McF: M[t2][col], col = wid*16+j
  unsigned short* McF = ws + WS_MCF;
  const int nRe = t2 >> 4, c16r = t2 & 15;
#pragma unroll
  for (int j = 0; j < 16; ++j) {
    int col = wid * 16 + j;
    int kk = col >> 5, gc = (col >> 3) & 3, e = col & 7;
    int off = (gc * 16 + c16r) * 8 + e;
    McF[(kk * 8 + nRe) * 512 + off]       = f2bf(mre[j]);
    McF[(kk * 8 + 4 + nRe) * 512 + off]   = f2bf(mim[j]);
  }
}

#define LDA 72
#define LDO 65

__global__ __launch_bounds__(256) void main_kernel(
    const float* __restrict__ b_in, const float* __restrict__ b_out,
    const unsigned short* __restrict__ ws, float* __restrict__ out)
{
  __shared__ __align__(16) unsigned char smem[18432];
  unsigned short* a_lds = (unsigned short*)smem;
  unsigned short* p_lds = (unsigned short*)(smem + 9216);
  float* o_lds = (float*)smem;

  const int tid = threadIdx.x, lane = tid & 63, wid = tid >> 6;
  const int g = lane >> 4, c16 = lane & 15;
  const int blk = blockIdx.x;
  const int b = blk >> 6, h = blk & 63;

  const unsigned short* WsF = ws + WS_WSF;
  const unsigned short* McF = ws + WS_MCF;
  const unsigned short* WoF = ws + WS_WOF;
  const unsigned short* xq = ws + WS_XBF + b * (CIN * HW * HW);

  // ---- GEMM1: xq[64 pix][64] = patch(64x288) * Ws^T + b_in ----
  f32x4 acc[4];
#pragma unroll
  for (int jt = 0; jt < 4; ++jt) { float bi = b_in[jt * 16 + c16]; acc[jt] = f32x4{bi, bi, bi, bi}; }

  const int ar = wid * 16 + c16;             // this lane's pixel w
#pragma unroll
  for (int kk = 0; kk < 9; ++kk) {
    const int di = kk / 3, dj = kk % 3;
    const int y = h + di - 1;
    const int xw = ar + dj - 1;
    const bool ok = ((unsigned)y < 64u) & ((unsigned)xw < 64u);
    const unsigned short* px = xq + y * 64 + xw;
    bf16x8 af;
#pragma unroll
    for (int i = 0; i < 8; ++i) {
      int cc = g * 8 + i;
      af[i] = (short)(ok ? px[cc * 4096] : (unsigned short)0);
    }
#pragma unroll
    for (int jt = 0; jt < 4; ++jt) {
      bf16x8 bf_ = *(const bf16x8*)(WsF + (kk * 4 + jt) * 512 + lane * 8);
      acc[jt] = __builtin_amdgcn_mfma_f32_16x16x32_bf16(af, bf_, acc[jt], 0, 0, 0);
    }
  }

  // ---- row norm (C layout: col=lane&15, row=(lane>>4)*4+reg) ----
  float s[4];
#pragma unroll
  for (int r = 0; r < 4; ++r) {
    float t = acc[0][r] * acc[0][r] + acc[1][r] * acc[1][r] +
              acc[2][r] * acc[2][r] + acc[3][r] * acc[3][r];
    t += __shfl_xor(t, 1); t += __shfl_xor(t, 2); t += __shfl_xor(t, 4); t += __shfl_xor(t, 8);
    s[r] = 1.f / (sqrtf(t) + 1e-9f);
  }
#pragma unroll
  for (int jt = 0; jt < 4; ++jt)
#pragma unroll
    for (int r = 0; r < 4; ++r)
      a_lds[(wid * 16 + g * 4 + r) * LDA + jt * 16 + c16] = f2bf(acc[jt][r] * s[r]);

  __syncthreads();

  // ---- circuit GEMM: [u|v](64x128) = a(64x64) * M^T (fragment-major B) ----
  f32x4 uv[8];
#pragma unroll
  for (int n = 0; n < 8; ++n) uv[n] = f32x4{0.f, 0.f, 0.f, 0.f};
#pragma unroll
  for (int kk = 0; kk < 2; ++kk) {
    bf16x8 af = *(const bf16x8*)(a_lds + (wid * 16 + c16) * LDA + kk * 32 + g * 8);
#pragma unroll
    for (int n = 0; n < 8; ++n) {
      bf16x8 bf_ = *(const bf16x8*)(McF + (kk * 8 + n) * 512 + lane * 8);
      uv[n] = __builtin_amdgcn_mfma_f32_16x16x32_bf16(af, bf_, uv[n], 0, 0, 0);
    }
  }

  // ---- probs = u^2 + v^2 ----
#pragma unroll
  for (int n = 0; n < 4; ++n)
#pragma unroll
    for (int r = 0; r < 4; ++r) {
      float p = uv[n][r] * uv[n][r] + uv[n + 4][r] * uv[n + 4][r];
      p_lds[(wid * 16 + g * 4 + r) * LDA + n * 16 + c16] = f2bf(p);
    }
  __syncthreads();

  // ---- out(64x64) = probs * Wout^T + b_out ----
  f32x4 o[4];
#pragma unroll
  for (int ot = 0; ot < 4; ++ot) { float bo = b_out[ot * 16 + c16]; o[ot] = f32x4{bo, bo, bo, bo}; }
#pragma unroll
  for (int kk = 0; kk < 2; ++kk) {
    bf16x8 af = *(const bf16x8*)(p_lds + (wid * 16 + c16) * LDA + kk * 32 + g * 8);
#pragma unroll
    for (int ot = 0; ot < 4; ++ot) {
      bf16x8 bf_ = *(const bf16x8*)(WoF + (kk * 4 + ot) * 512 + lane * 8);
      o[ot] = __builtin_amdgcn_mfma_f32_16x16x32_bf16(af, bf_, o[ot], 0, 0, 0);
    }
  }

  __syncthreads();
#pragma unroll
  for (int ot = 0; ot < 4; ++ot)
#pragma unroll
    for (int r = 0; r < 4; ++r)
      o_lds[(ot * 16 + c16) * LDO + wid * 16 + g * 4 + r] = o[ot][r];
  __syncthreads();

  float* outb = out + (size_t)b * QD * HW * HW + h * HW;
#pragma unroll
  for (int it = 0; it < 16; ++it) {
    int orow = it * 4 + wid;
    outb[orow * (HW * HW) + lane] = o_lds[orow * LDO + lane];
  }
}

extern "C" void kernel_launch(void* const* d_in, const int* in_sizes, int n_in,
                              void* d_out, int out_size, void* d_ws, size_t ws_size,
                              hipStream_t stream) {
  const float* x          = (const float*)d_in[0];
  const float* inp_scale  = (const float*)d_in[1];
  const float* in_proj_w  = (const float*)d_in[2];
  const float* in_proj_b  = (const float*)d_in[3];
  const float* weights    = (const float*)d_in[4];
  const float* meas_w     = (const float*)d_in[5];
  const float* out_proj_w = (const float*)d_in[6];
  const float* out_proj_b = (const float*)d_in[7];
  unsigned short* ws = (unsigned short*)d_ws;

  prep_kernel<<<1062, 256, 0, stream>>>(x, in_proj_w, inp_scale, weights, meas_w, out_proj_w, ws);
  main_kernel<<<NB * HW, 256, 0, stream>>>(in_proj_b, out_proj_b, ws, (float*)d_out);
}